// Round 8
// baseline (453.777 us; speedup 1.0000x reference)
//
#include <hip/hip_runtime.h>

#define NODE_DIM 8

typedef __attribute__((ext_vector_type(8))) short short8;
typedef __attribute__((ext_vector_type(4))) float f32x4;

// 8-term dot; param must not be named w/x/y/z (macro hits member access).
#define DOT8(xv, WT) ((xv)[0]*(WT)[0] + (xv)[1]*(WT)[1] + (xv)[2]*(WT)[2] + (xv)[3]*(WT)[3] + \
                      (xv)[4]*(WT)[4] + (xv)[5]*(WT)[5] + (xv)[6]*(WT)[6] + (xv)[7]*(WT)[7])

// RNE fp32->bf16, packed pair (a -> low16, b -> high16).
static __device__ __forceinline__ unsigned pk_bf16(float a, float b) {
    unsigned ua = __float_as_uint(a), ub = __float_as_uint(b);
    ua = (ua + 0x7fffu + ((ua >> 16) & 1u)) >> 16;
    ub = (ub + 0x7fffu + ((ub >> 16) & 1u)) & 0xffff0000u;
    return (ua & 0xffffu) | ub;
}

// ===========================================================================
// CSR build: histogram -> prefix scan -> permutation scatter.
// ===========================================================================
__global__ __launch_bounds__(256)
void hist_kernel(const int* __restrict__ eidx, int* __restrict__ cnt, int E)
{
    const int e = blockIdx.x * blockDim.x + threadIdx.x;
    if (e < E) atomicAdd(&cnt[eidx[E + e]], 1);
}

__global__ __launch_bounds__(1024)
void scan_kernel(const int* __restrict__ cnt, int* __restrict__ rowptr,
                 int* __restrict__ next, int N, int E)
{
    __shared__ int part[1024];
    const int t  = threadIdx.x;
    const int CH = (N + 1023) >> 10;
    const int lo = t * CH;
    const int hi = (lo + CH < N) ? lo + CH : N;

    int sum = 0;
    for (int i = lo; i < hi; ++i) sum += cnt[i];
    part[t] = sum;
    __syncthreads();

    for (int off = 1; off < 1024; off <<= 1) {
        const int v = (t >= off) ? part[t - off] : 0;
        __syncthreads();
        part[t] += v;
        __syncthreads();
    }

    int run = (t == 0) ? 0 : part[t - 1];
    for (int i = lo; i < hi; ++i) {
        rowptr[i] = run;
        next[i]   = run;
        run += cnt[i];
    }
    if (t == 1023) rowptr[N] = E;
}

__global__ __launch_bounds__(256)
void scatter_kernel(const int* __restrict__ eidx, int* __restrict__ next,
                    int* __restrict__ perm, int E)
{
    const int e = blockIdx.x * blockDim.x + threadIdx.x;
    if (e < E) {
        const int pos = atomicAdd(&next[eidx[E + e]], 1);
        perm[pos] = e;
    }
}

// ===========================================================================
// Edge kernel (CSR path): identical MFMA math to R7 but edges processed in
// dst-sorted order (via perm) and msg written DENSE, non-atomic, coalesced.
//   [E,256]@[256,32]; f[e, c=(k<<3|i)] = h[e,k]*x[src[e],i].
//   A-frag: a_j = h[e, 4kk+q]*x[e,j] (8 mul + 4 pack, no shuffle).
//   B staged bf16 in LDS in frag order (18 KB). C: col=lane&15, row=q*4+r.
// ===========================================================================
__global__ __launch_bounds__(256)
void edge_kernel_csr(const float* __restrict__ x,
                     const float* __restrict__ ea,
                     const int* __restrict__ eidx,
                     const int* __restrict__ perm,
                     const float* __restrict__ W1, const float* __restrict__ b1,
                     const float* __restrict__ W2, const float* __restrict__ b2,
                     float* __restrict__ msg, int E)
{
    __shared__ __align__(16) short lds_b[18 * 64 * 8];
    const int t = threadIdx.x;

    for (int f = t; f < 18 * 64 * 8; f += 256) {
        const int j   = f & 7;
        const int ln  = (f >> 3) & 63;
        const int fid = f >> 9;
        const int kk  = fid >> 1, ot = fid & 1;
        const int qq  = ln >> 4, ol = ln & 15;
        float v;
        if (kk < 8) v = W2[(kk * 4 + qq) * 256 + j * 32 + ot * 16 + ol];
        else        v = (qq == 0) ? b2[j * 32 + ot * 16 + ol] : 0.f;
        unsigned uv = __float_as_uint(v);
        uv = (uv + 0x7fffu + ((uv >> 16) & 1u)) >> 16;
        lds_b[f] = (short)uv;
    }
    __syncthreads();

    const int lane = t & 63;
    const int e_l  = lane & 15;
    const int q    = lane >> 4;

    float w10[8], w11[8], w12[8], b1r[8];
#pragma unroll
    for (int t2 = 0; t2 < 8; ++t2) {
        const int k = 4 * t2 + q;
        w10[t2] = W1[k]; w11[t2] = W1[32 + k]; w12[t2] = W1[64 + k]; b1r[t2] = b1[k];
    }

    const int wave = blockIdx.x * 4 + (t >> 6);
    const int nwav = gridDim.x * 4;
    const int ngrp = (E + 15) / 16;

    for (int grp = wave; grp < ngrp; grp += nwav) {
        const int base = grp * 16;
        int slot = base + e_l; if (slot >= E) slot = E - 1;
        const int ej  = perm[slot];
        const int src = eidx[ej];
        const float ea0 = ea[3 * ej], ea1 = ea[3 * ej + 1], ea2 = ea[3 * ej + 2];
        const float4 xa = *(const float4*)(x + (size_t)(unsigned)src * 8);
        const float4 xb = *(const float4*)(x + (size_t)(unsigned)src * 8 + 4);
        const float xr[8] = {xa.x, xa.y, xa.z, xa.w, xb.x, xb.y, xb.z, xb.w};

        float h[8];
#pragma unroll
        for (int t2 = 0; t2 < 8; ++t2) {
            const float z = b1r[t2] + ea0 * w10[t2] + ea1 * w11[t2] + ea2 * w12[t2];
            h[t2] = z > 0.f ? z : 0.f;
        }

        f32x4 acc0 = {0.f, 0.f, 0.f, 0.f};
        f32x4 acc1 = {0.f, 0.f, 0.f, 0.f};

#pragma unroll
        for (int kk = 0; kk < 9; ++kk) {
            const float hk = (kk < 8) ? h[kk] : 1.f;
            union { short8 v; unsigned u[4]; } af;
#pragma unroll
            for (int p = 0; p < 4; ++p)
                af.u[p] = pk_bf16(hk * xr[2 * p], hk * xr[2 * p + 1]);
            const short8 bf0 = *(const short8*)&lds_b[((kk * 2 + 0) * 64 + lane) * 8];
            const short8 bf1 = *(const short8*)&lds_b[((kk * 2 + 1) * 64 + lane) * 8];
            acc0 = __builtin_amdgcn_mfma_f32_16x16x32_bf16(af.v, bf0, acc0, 0, 0, 0);
            acc1 = __builtin_amdgcn_mfma_f32_16x16x32_bf16(af.v, bf1, acc1, 0, 0, 0);
        }

        // Dense store: row = sorted slot base+q*4+r; cols e_l and 16+e_l.
#pragma unroll
        for (int r = 0; r < 4; ++r) {
            const int row = base + q * 4 + r;
            if (row < E) {
                msg[(size_t)row * 32 + e_l]      = acc0[r];
                msg[(size_t)row * 32 + 16 + e_l] = acc1[r];
            }
        }
    }
}

// ===========================================================================
// Gather + node transform + pool (CSR path): per node, msg rows are now
// CONTIGUOUS [rowptr[n], rowptr[n+1]) -> coalesced, zero atomics for s.
// 256 threads = 8 nodes x 32 dims; block-local pool -> gsum atomics.
// ===========================================================================
__global__ __launch_bounds__(256)
void gather_pool_kernel(const float* __restrict__ msg,
                        const int* __restrict__ rowptr,
                        const float* __restrict__ x,
                        const float* __restrict__ root,
                        const float* __restrict__ conv_bias,
                        const int* __restrict__ batch,
                        float* __restrict__ gsum, int N)
{
    __shared__ float red[256];
    const int t    = threadIdx.x;
    const int o    = t & 31;
    const int slot = t >> 5;
    const int base = blockIdx.x * 8;
    const int n    = base + slot;

    float rootr[8];
#pragma unroll
    for (int i = 0; i < 8; ++i) rootr[i] = root[i * 32 + o];
    const float cb = conv_bias[o];

    float v = 0.f;
    int   b = 0;
    if (n < N) {
        b = batch[n];
        const int startp = rowptr[n], endp = rowptr[n + 1];
        float sum = 0.f;
        int i = startp;
        for (; i + 1 < endp; i += 2)
            sum += msg[(size_t)i * 32 + o] + msg[(size_t)(i + 1) * 32 + o];
        if (i < endp) sum += msg[(size_t)i * 32 + o];
        const int   c    = endp - startp;
        const float rinv = 1.f / (float)(c > 1 ? c : 1);
        const float* xp  = x + (size_t)n * 8;
        float xv[8];
#pragma unroll
        for (int k = 0; k < 8; ++k) xv[k] = xp[k];
        const float t2 = sum * rinv + cb + DOT8(xv, rootr);
        v = t2 > 0.f ? t2 : 0.f;
    }

    const int nlast  = (base + 7 < N) ? base + 7 : N - 1;
    const int bfirst = batch[base];
    const int blast  = batch[nlast];

    if (bfirst == blast && base + 7 < N) {
        red[t] = v;
        __syncthreads();
        if (t < 32) {
            float p = 0.f;
#pragma unroll
            for (int c2 = 0; c2 < 8; ++c2) p += red[t + 32 * c2];
            atomicAdd(&gsum[bfirst * 32 + t], p);
        }
    } else {
        if (n < N) atomicAdd(&gsum[b * 32 + o], v);
    }
}

// ===========================================================================
// Fallback path kernels (R7): atomic scatter into s, then node_pool.
// ===========================================================================
__global__ __launch_bounds__(256)
void edge_kernel_atomic(const float* __restrict__ x,
                        const float* __restrict__ ea,
                        const int* __restrict__ eidx,
                        const float* __restrict__ W1, const float* __restrict__ b1,
                        const float* __restrict__ W2, const float* __restrict__ b2,
                        float* __restrict__ s, int* __restrict__ cnt,
                        int E)
{
    __shared__ __align__(16) short lds_b[18 * 64 * 8];
    const int t = threadIdx.x;

    for (int f = t; f < 18 * 64 * 8; f += 256) {
        const int j   = f & 7;
        const int ln  = (f >> 3) & 63;
        const int fid = f >> 9;
        const int kk  = fid >> 1, ot = fid & 1;
        const int qq  = ln >> 4, ol = ln & 15;
        float v;
        if (kk < 8) v = W2[(kk * 4 + qq) * 256 + j * 32 + ot * 16 + ol];
        else        v = (qq == 0) ? b2[j * 32 + ot * 16 + ol] : 0.f;
        unsigned uv = __float_as_uint(v);
        uv = (uv + 0x7fffu + ((uv >> 16) & 1u)) >> 16;
        lds_b[f] = (short)uv;
    }
    __syncthreads();

    const int lane = t & 63;
    const int e_l  = lane & 15;
    const int q    = lane >> 4;

    float w10[8], w11[8], w12[8], b1r[8];
#pragma unroll
    for (int t2 = 0; t2 < 8; ++t2) {
        const int k = 4 * t2 + q;
        w10[t2] = W1[k]; w11[t2] = W1[32 + k]; w12[t2] = W1[64 + k]; b1r[t2] = b1[k];
    }

    const int wave = blockIdx.x * 4 + (t >> 6);
    const int nwav = gridDim.x * 4;
    const int ngrp = (E + 15) / 16;

    for (int grp = wave; grp < ngrp; grp += nwav) {
        const int base = grp * 16;
        int ej = base + e_l; if (ej >= E) ej = E - 1;
        const int src = eidx[ej];
        const int dst = eidx[E + ej];
        const float ea0 = ea[3 * ej], ea1 = ea[3 * ej + 1], ea2 = ea[3 * ej + 2];
        const float4 xa = *(const float4*)(x + (size_t)(unsigned)src * 8);
        const float4 xb = *(const float4*)(x + (size_t)(unsigned)src * 8 + 4);
        const float xr[8] = {xa.x, xa.y, xa.z, xa.w, xb.x, xb.y, xb.z, xb.w};

        float h[8];
#pragma unroll
        for (int t2 = 0; t2 < 8; ++t2) {
            const float z = b1r[t2] + ea0 * w10[t2] + ea1 * w11[t2] + ea2 * w12[t2];
            h[t2] = z > 0.f ? z : 0.f;
        }

        f32x4 acc0 = {0.f, 0.f, 0.f, 0.f};
        f32x4 acc1 = {0.f, 0.f, 0.f, 0.f};

#pragma unroll
        for (int kk = 0; kk < 9; ++kk) {
            const float hk = (kk < 8) ? h[kk] : 1.f;
            union { short8 v; unsigned u[4]; } af;
#pragma unroll
            for (int p = 0; p < 4; ++p)
                af.u[p] = pk_bf16(hk * xr[2 * p], hk * xr[2 * p + 1]);
            const short8 bf0 = *(const short8*)&lds_b[((kk * 2 + 0) * 64 + lane) * 8];
            const short8 bf1 = *(const short8*)&lds_b[((kk * 2 + 1) * 64 + lane) * 8];
            acc0 = __builtin_amdgcn_mfma_f32_16x16x32_bf16(af.v, bf0, acc0, 0, 0, 0);
            acc1 = __builtin_amdgcn_mfma_f32_16x16x32_bf16(af.v, bf1, acc1, 0, 0, 0);
        }

#pragma unroll
        for (int r = 0; r < 4; ++r) {
            const int m  = q * 4 + r;
            const int eg = base + m;
            const int dr = __shfl(dst, m, 16);
            if (eg < E) {
                atomicAdd(&s[(size_t)(unsigned)dr * 32 + e_l],      acc0[r]);
                atomicAdd(&s[(size_t)(unsigned)dr * 32 + 16 + e_l], acc1[r]);
            }
        }
        if (lane < 16 && base + e_l < E) atomicAdd(&cnt[dst], 1);
    }
}

__global__ __launch_bounds__(256)
void node_pool_kernel(const float* __restrict__ s,
                      const int* __restrict__ cnt,
                      const float* __restrict__ x,
                      const float* __restrict__ root,
                      const float* __restrict__ conv_bias,
                      const int* __restrict__ batch,
                      float* __restrict__ gsum, int N)
{
    __shared__ float red[256];
    const int t    = threadIdx.x;
    const int o    = t & 31;
    const int slot = t >> 5;
    const int base = blockIdx.x * 8;
    const int n    = base + slot;

    float rootr[8];
#pragma unroll
    for (int i = 0; i < 8; ++i) rootr[i] = root[i * 32 + o];
    const float cb = conv_bias[o];

    float v = 0.f;
    int   b = 0;
    if (n < N) {
        b = batch[n];
        const int   c    = cnt[n];
        const float rinv = 1.f / (float)(c > 1 ? c : 1);
        const float* xp  = x + (size_t)n * 8;
        float xv[8];
#pragma unroll
        for (int i = 0; i < 8; ++i) xv[i] = xp[i];
        const float t2 = s[(size_t)n * 32 + o] * rinv + cb + DOT8(xv, rootr);
        v = t2 > 0.f ? t2 : 0.f;
    }

    const int nlast  = (base + 7 < N) ? base + 7 : N - 1;
    const int bfirst = batch[base];
    const int blast  = batch[nlast];

    if (bfirst == blast && base + 7 < N) {
        red[t] = v;
        __syncthreads();
        if (t < 32) {
            float p = 0.f;
#pragma unroll
            for (int c2 = 0; c2 < 8; ++c2) p += red[t + 32 * c2];
            atomicAdd(&gsum[bfirst * 32 + t], p);
        }
    } else {
        if (n < N) atomicAdd(&gsum[b * 32 + o], v);
    }
}

// ===========================================================================
// MLP head: one 128-thread block per graph.
// ===========================================================================
__global__ __launch_bounds__(128)
void mlp_kernel(const float* __restrict__ gsum,
                const int* __restrict__ batch,
                const float* __restrict__ ratios,
                const int* __restrict__ ids,
                const float* __restrict__ emb,
                const float* __restrict__ fc0w, const float* __restrict__ fc0b,
                const float* __restrict__ fc1w, const float* __restrict__ fc1b,
                const float* __restrict__ fc2w, const float* __restrict__ fc2b,
                float* __restrict__ out, int N)
{
    __shared__ float zs[96];
    __shared__ float z1[64];
    __shared__ float z2[32];
    __shared__ int seg[2];

    const int g = blockIdx.x;
    const int t = threadIdx.x;

    if (t < 2) {
        const int target = g + t;
        int lo = 0, hi = N;
        while (lo < hi) {
            const int mid = (lo + hi) >> 1;
            if (batch[mid] < target) lo = mid + 1; else hi = mid;
        }
        seg[t] = lo;
    }
    __syncthreads();

    float c = (float)(seg[1] - seg[0]);
    if (c < 1.f) c = 1.f;

    if (t < 32) zs[t] = gsum[g * 32 + t] / c;
    if (t >= 32 && t < 96) {
        const int j = t - 32;
        float u = 0.f;
#pragma unroll
        for (int r = 0; r < 5; ++r) u += ratios[r] * emb[(size_t)ids[r] * 64 + j];
        zs[32 + j] = u;
    }
    __syncthreads();

    if (t < 64) {
        float a = fc0b[t];
        for (int k = 0; k < 96; ++k) a += zs[k] * fc0w[k * 64 + t];
        z1[t] = a > 0.f ? a : 0.f;
    }
    __syncthreads();

    if (t < 32) {
        float a = fc1b[t];
        for (int k = 0; k < 64; ++k) a += z1[k] * fc1w[k * 32 + t];
        z2[t] = a > 0.f ? a : 0.f;
    }
    __syncthreads();

    if (t == 0) {
        float a = fc2b[0];
        for (int k = 0; k < 32; ++k) a += z2[k] * fc2w[k];
        out[g] = a;
    }
}

// ---------------------------------------------------------------------------
extern "C" void kernel_launch(void* const* d_in, const int* in_sizes, int n_in,
                              void* d_out, int out_size, void* d_ws, size_t ws_size,
                              hipStream_t stream)
{
    const float* x         = (const float*)d_in[0];
    const float* ea        = (const float*)d_in[1];
    const float* ratios    = (const float*)d_in[2];
    const int*   eidx      = (const int*)  d_in[3];
    const int*   batch     = (const int*)  d_in[4];
    const int*   ids       = (const int*)  d_in[5];
    const float* W1        = (const float*)d_in[6];
    const float* b1        = (const float*)d_in[7];
    const float* W2        = (const float*)d_in[8];
    const float* b2        = (const float*)d_in[9];
    const float* emb       = (const float*)d_in[10];
    const float* root      = (const float*)d_in[11];
    const float* conv_bias = (const float*)d_in[12];
    const float* fc0w      = (const float*)d_in[13];
    const float* fc0b      = (const float*)d_in[14];
    const float* fc1w      = (const float*)d_in[15];
    const float* fc1b      = (const float*)d_in[16];
    const float* fc2w      = (const float*)d_in[17];
    const float* fc2b      = (const float*)d_in[18];

    const int N = in_sizes[0] / NODE_DIM;   // 50000
    const int E = in_sizes[1] / 3;          // 1000000
    const int G = out_size;                 // 128

    // CSR-path workspace layout
    char* p = (char*)d_ws;
    float* msg    = (float*)p;                      p += (size_t)E * 32 * 4;   // [E,32]
    int*   perm   = (int*)p;                        p += (size_t)E * 4;        // [E]
    int*   rowptr = (int*)p;                        p += (size_t)(N + 1) * 4;  // [N+1]
    int*   nxt    = (int*)p;                        p += (size_t)N * 4;        // [N]
    int*   cnt    = (int*)p;                        p += (size_t)N * 4;        // [N]  (zeroed)
    float* gsum   = (float*)p;                      p += (size_t)G * 32 * 4;   // [G,32] (zeroed)
    const size_t need_csr = (size_t)(p - (char*)d_ws);

    if (ws_size >= need_csr) {
        // cnt and gsum are adjacent -> one memset
        (void)hipMemsetAsync(cnt, 0, (size_t)N * 4 + (size_t)G * 32 * 4, stream);
        hist_kernel<<<(E + 255) / 256, 256, 0, stream>>>(eidx, cnt, E);
        scan_kernel<<<1, 1024, 0, stream>>>(cnt, rowptr, nxt, N, E);
        scatter_kernel<<<(E + 255) / 256, 256, 0, stream>>>(eidx, nxt, perm, E);
        edge_kernel_csr<<<2048, 256, 0, stream>>>(x, ea, eidx, perm,
                                                  W1, b1, W2, b2, msg, E);
        gather_pool_kernel<<<(N + 7) / 8, 256, 0, stream>>>(msg, rowptr, x, root,
                                                            conv_bias, batch, gsum, N);
        mlp_kernel<<<G, 128, 0, stream>>>(gsum, batch, ratios, ids, emb,
                                          fc0w, fc0b, fc1w, fc1b, fc2w, fc2b,
                                          (float*)d_out, N);
    } else {
        // Fallback: R7 atomic-scatter path (s[N,32] + cnt[N] + gsum[G,32])
        float* s2    = (float*)d_ws;
        int*   cnt2  = (int*)((char*)d_ws + (size_t)N * 32 * 4);
        float* gsum2 = (float*)((char*)d_ws + (size_t)N * 32 * 4 + (size_t)N * 4);
        (void)hipMemsetAsync(d_ws, 0, (size_t)N * 32 * 4 + (size_t)N * 4 + (size_t)G * 32 * 4, stream);
        edge_kernel_atomic<<<2048, 256, 0, stream>>>(x, ea, eidx, W1, b1, W2, b2,
                                                     s2, cnt2, E);
        node_pool_kernel<<<(N + 7) / 8, 256, 0, stream>>>(s2, cnt2, x, root, conv_bias,
                                                          batch, gsum2, N);
        mlp_kernel<<<G, 128, 0, stream>>>(gsum2, batch, ratios, ids, emb,
                                          fc0w, fc0b, fc1w, fc1b, fc2w, fc2b,
                                          (float*)d_out, N);
    }
}

// Round 9
// 358.863 us; speedup vs baseline: 1.2645x; 1.2645x over previous
//
#include <hip/hip_runtime.h>

#define NODE_DIM 8

typedef __attribute__((ext_vector_type(8))) short short8;
typedef __attribute__((ext_vector_type(4))) float f32x4;

// 8-term dot; param must not be named w/x/y/z (macro hits member access).
#define DOT8(xv, WT) ((xv)[0]*(WT)[0] + (xv)[1]*(WT)[1] + (xv)[2]*(WT)[2] + (xv)[3]*(WT)[3] + \
                      (xv)[4]*(WT)[4] + (xv)[5]*(WT)[5] + (xv)[6]*(WT)[6] + (xv)[7]*(WT)[7])

// RNE fp32->bf16, packed pair (a -> low16, b -> high16).
static __device__ __forceinline__ unsigned pk_bf16(float a, float b) {
    unsigned ua = __float_as_uint(a), ub = __float_as_uint(b);
    ua = (ua + 0x7fffu + ((ua >> 16) & 1u)) >> 16;
    ub = (ub + 0x7fffu + ((ub >> 16) & 1u)) & 0xffff0000u;
    return (ua & 0xffffu) | ub;
}

// ===========================================================================
// CSR build: histogram -> 3-stage hierarchical scan -> permutation scatter.
// R8 post-mortem: single-block scan was 112 us (one CU, serial chunks).
// ===========================================================================
__global__ __launch_bounds__(256)
void hist_kernel(const int* __restrict__ eidx, int* __restrict__ cnt, int E)
{
    const int e = blockIdx.x * blockDim.x + threadIdx.x;
    if (e < E) atomicAdd(&cnt[eidx[E + e]], 1);
}

// Stage 1: block-local exclusive scan of cnt -> rowptr (per-block prefix),
// block totals -> bsum.
__global__ __launch_bounds__(256)
void scan1_kernel(const int* __restrict__ cnt, int* __restrict__ rowptr,
                  int* __restrict__ bsum, int N)
{
    __shared__ int sh[256];
    const int t = threadIdx.x;
    const int i = blockIdx.x * 256 + t;
    const int v = (i < N) ? cnt[i] : 0;
    sh[t] = v;
    __syncthreads();
#pragma unroll
    for (int off = 1; off < 256; off <<= 1) {
        int add = 0;
        if (t >= off) add = sh[t - off];
        __syncthreads();
        if (t >= off) sh[t] += add;
        __syncthreads();
    }
    if (i < N) rowptr[i] = sh[t] - v;            // exclusive within block
    if (t == 255) bsum[blockIdx.x] = sh[255];    // block total
}

// Stage 2: one block scans the (<=256) block sums -> exclusive offsets.
__global__ __launch_bounds__(256)
void scan2_kernel(const int* __restrict__ bsum, int* __restrict__ boff, int NB)
{
    __shared__ int sh[256];
    const int t = threadIdx.x;
    const int v = (t < NB) ? bsum[t] : 0;
    sh[t] = v;
    __syncthreads();
#pragma unroll
    for (int off = 1; off < 256; off <<= 1) {
        int add = 0;
        if (t >= off) add = sh[t - off];
        __syncthreads();
        if (t >= off) sh[t] += add;
        __syncthreads();
    }
    if (t < NB) boff[t] = sh[t] - v;
}

// Stage 3: add block offsets, mirror into next[], close rowptr.
__global__ __launch_bounds__(256)
void scan3_kernel(int* __restrict__ rowptr, int* __restrict__ nxt,
                  const int* __restrict__ boff, int N, int E)
{
    const int i = blockIdx.x * 256 + threadIdx.x;
    if (i < N) {
        const int r = rowptr[i] + boff[i >> 8];
        rowptr[i] = r;
        nxt[i]    = r;
    }
    if (i == 0) rowptr[N] = E;
}

__global__ __launch_bounds__(256)
void scatter_kernel(const int* __restrict__ eidx, int* __restrict__ nxt,
                    int* __restrict__ perm, int E)
{
    const int e = blockIdx.x * blockDim.x + threadIdx.x;
    if (e < E) {
        const int pos = atomicAdd(&nxt[eidx[E + e]], 1);
        perm[pos] = e;
    }
}

// ===========================================================================
// Edge kernel (CSR): [E,256]@[256,32] via MFMA 16x16x32_bf16; edges in
// dst-sorted order (perm), msg written DENSE, non-atomic, coalesced.
//   f[e, c=(k<<3|i)] = h[e,k]*x[src[e],i]; A-frag a_j = h[e,4kk+q]*x[e,j]
//   (8 mul + 4 pack, no shuffle). B (W2R + b2 row-ext) staged bf16 in LDS in
//   frag order (18 KB). C: col=lane&15, row=q*4+r.
// ===========================================================================
__global__ __launch_bounds__(256)
void edge_kernel_csr(const float* __restrict__ x,
                     const float* __restrict__ ea,
                     const int* __restrict__ eidx,
                     const int* __restrict__ perm,
                     const float* __restrict__ W1, const float* __restrict__ b1,
                     const float* __restrict__ W2, const float* __restrict__ b2,
                     float* __restrict__ msg, int E)
{
    __shared__ __align__(16) short lds_b[18 * 64 * 8];
    const int t = threadIdx.x;

    for (int f = t; f < 18 * 64 * 8; f += 256) {
        const int j   = f & 7;
        const int ln  = (f >> 3) & 63;
        const int fid = f >> 9;
        const int kk  = fid >> 1, ot = fid & 1;
        const int qq  = ln >> 4, ol = ln & 15;
        float v;
        if (kk < 8) v = W2[(kk * 4 + qq) * 256 + j * 32 + ot * 16 + ol];
        else        v = (qq == 0) ? b2[j * 32 + ot * 16 + ol] : 0.f;
        unsigned uv = __float_as_uint(v);
        uv = (uv + 0x7fffu + ((uv >> 16) & 1u)) >> 16;
        lds_b[f] = (short)uv;
    }
    __syncthreads();

    const int lane = t & 63;
    const int e_l  = lane & 15;
    const int q    = lane >> 4;

    float w10[8], w11[8], w12[8], b1r[8];
#pragma unroll
    for (int t2 = 0; t2 < 8; ++t2) {
        const int k = 4 * t2 + q;
        w10[t2] = W1[k]; w11[t2] = W1[32 + k]; w12[t2] = W1[64 + k]; b1r[t2] = b1[k];
    }

    const int wave = blockIdx.x * 4 + (t >> 6);
    const int nwav = gridDim.x * 4;
    const int ngrp = (E + 15) / 16;

    for (int grp = wave; grp < ngrp; grp += nwav) {
        const int base = grp * 16;
        int slot = base + e_l; if (slot >= E) slot = E - 1;
        const int ej  = perm[slot];
        const int src = eidx[ej];
        const float ea0 = ea[3 * ej], ea1 = ea[3 * ej + 1], ea2 = ea[3 * ej + 2];
        const float4 xa = *(const float4*)(x + (size_t)(unsigned)src * 8);
        const float4 xb = *(const float4*)(x + (size_t)(unsigned)src * 8 + 4);
        const float xr[8] = {xa.x, xa.y, xa.z, xa.w, xb.x, xb.y, xb.z, xb.w};

        float h[8];
#pragma unroll
        for (int t2 = 0; t2 < 8; ++t2) {
            const float z = b1r[t2] + ea0 * w10[t2] + ea1 * w11[t2] + ea2 * w12[t2];
            h[t2] = z > 0.f ? z : 0.f;
        }

        f32x4 acc0 = {0.f, 0.f, 0.f, 0.f};
        f32x4 acc1 = {0.f, 0.f, 0.f, 0.f};

#pragma unroll
        for (int kk = 0; kk < 9; ++kk) {
            const float hk = (kk < 8) ? h[kk] : 1.f;
            union { short8 v; unsigned u[4]; } af;
#pragma unroll
            for (int p = 0; p < 4; ++p)
                af.u[p] = pk_bf16(hk * xr[2 * p], hk * xr[2 * p + 1]);
            const short8 bf0 = *(const short8*)&lds_b[((kk * 2 + 0) * 64 + lane) * 8];
            const short8 bf1 = *(const short8*)&lds_b[((kk * 2 + 1) * 64 + lane) * 8];
            acc0 = __builtin_amdgcn_mfma_f32_16x16x32_bf16(af.v, bf0, acc0, 0, 0, 0);
            acc1 = __builtin_amdgcn_mfma_f32_16x16x32_bf16(af.v, bf1, acc1, 0, 0, 0);
        }

#pragma unroll
        for (int r = 0; r < 4; ++r) {
            const int row = base + q * 4 + r;
            if (row < E) {
                msg[(size_t)row * 32 + e_l]      = acc0[r];
                msg[(size_t)row * 32 + 16 + e_l] = acc1[r];
            }
        }
    }
}

// ===========================================================================
// Gather + node transform + pool: per node, msg rows contiguous
// [rowptr[n], rowptr[n+1]) -> coalesced, zero fp32 scatter atomics.
// ===========================================================================
__global__ __launch_bounds__(256)
void gather_pool_kernel(const float* __restrict__ msg,
                        const int* __restrict__ rowptr,
                        const float* __restrict__ x,
                        const float* __restrict__ root,
                        const float* __restrict__ conv_bias,
                        const int* __restrict__ batch,
                        float* __restrict__ gsum, int N)
{
    __shared__ float red[256];
    const int t    = threadIdx.x;
    const int o    = t & 31;
    const int slot = t >> 5;
    const int base = blockIdx.x * 8;
    const int n    = base + slot;

    float rootr[8];
#pragma unroll
    for (int i = 0; i < 8; ++i) rootr[i] = root[i * 32 + o];
    const float cb = conv_bias[o];

    float v = 0.f;
    int   b = 0;
    if (n < N) {
        b = batch[n];
        const int startp = rowptr[n], endp = rowptr[n + 1];
        float sum = 0.f;
        int i = startp;
        for (; i + 1 < endp; i += 2)
            sum += msg[(size_t)i * 32 + o] + msg[(size_t)(i + 1) * 32 + o];
        if (i < endp) sum += msg[(size_t)i * 32 + o];
        const int   c    = endp - startp;
        const float rinv = 1.f / (float)(c > 1 ? c : 1);
        const float* xp  = x + (size_t)n * 8;
        float xv[8];
#pragma unroll
        for (int k = 0; k < 8; ++k) xv[k] = xp[k];
        const float t2 = sum * rinv + cb + DOT8(xv, rootr);
        v = t2 > 0.f ? t2 : 0.f;
    }

    const int nlast  = (base + 7 < N) ? base + 7 : N - 1;
    const int bfirst = batch[base];
    const int blast  = batch[nlast];

    if (bfirst == blast && base + 7 < N) {
        red[t] = v;
        __syncthreads();
        if (t < 32) {
            float p = 0.f;
#pragma unroll
            for (int c2 = 0; c2 < 8; ++c2) p += red[t + 32 * c2];
            atomicAdd(&gsum[bfirst * 32 + t], p);
        }
    } else {
        if (n < N) atomicAdd(&gsum[b * 32 + o], v);
    }
}

// ===========================================================================
// MLP head: one 128-thread block per graph.
// ===========================================================================
__global__ __launch_bounds__(128)
void mlp_kernel(const float* __restrict__ gsum,
                const int* __restrict__ batch,
                const float* __restrict__ ratios,
                const int* __restrict__ ids,
                const float* __restrict__ emb,
                const float* __restrict__ fc0w, const float* __restrict__ fc0b,
                const float* __restrict__ fc1w, const float* __restrict__ fc1b,
                const float* __restrict__ fc2w, const float* __restrict__ fc2b,
                float* __restrict__ out, int N)
{
    __shared__ float zs[96];
    __shared__ float z1[64];
    __shared__ float z2[32];
    __shared__ int seg[2];

    const int g = blockIdx.x;
    const int t = threadIdx.x;

    if (t < 2) {
        const int target = g + t;
        int lo = 0, hi = N;
        while (lo < hi) {
            const int mid = (lo + hi) >> 1;
            if (batch[mid] < target) lo = mid + 1; else hi = mid;
        }
        seg[t] = lo;
    }
    __syncthreads();

    float c = (float)(seg[1] - seg[0]);
    if (c < 1.f) c = 1.f;

    if (t < 32) zs[t] = gsum[g * 32 + t] / c;
    if (t >= 32 && t < 96) {
        const int j = t - 32;
        float u = 0.f;
#pragma unroll
        for (int r = 0; r < 5; ++r) u += ratios[r] * emb[(size_t)ids[r] * 64 + j];
        zs[32 + j] = u;
    }
    __syncthreads();

    if (t < 64) {
        float a = fc0b[t];
        for (int k = 0; k < 96; ++k) a += zs[k] * fc0w[k * 64 + t];
        z1[t] = a > 0.f ? a : 0.f;
    }
    __syncthreads();

    if (t < 32) {
        float a = fc1b[t];
        for (int k = 0; k < 64; ++k) a += z1[k] * fc1w[k * 32 + t];
        z2[t] = a > 0.f ? a : 0.f;
    }
    __syncthreads();

    if (t == 0) {
        float a = fc2b[0];
        for (int k = 0; k < 32; ++k) a += z2[k] * fc2w[k];
        out[g] = a;
    }
}

// ---------------------------------------------------------------------------
extern "C" void kernel_launch(void* const* d_in, const int* in_sizes, int n_in,
                              void* d_out, int out_size, void* d_ws, size_t ws_size,
                              hipStream_t stream)
{
    const float* x         = (const float*)d_in[0];
    const float* ea        = (const float*)d_in[1];
    const float* ratios    = (const float*)d_in[2];
    const int*   eidx      = (const int*)  d_in[3];
    const int*   batch     = (const int*)  d_in[4];
    const int*   ids       = (const int*)  d_in[5];
    const float* W1        = (const float*)d_in[6];
    const float* b1        = (const float*)d_in[7];
    const float* W2        = (const float*)d_in[8];
    const float* b2        = (const float*)d_in[9];
    const float* emb       = (const float*)d_in[10];
    const float* root      = (const float*)d_in[11];
    const float* conv_bias = (const float*)d_in[12];
    const float* fc0w      = (const float*)d_in[13];
    const float* fc0b      = (const float*)d_in[14];
    const float* fc1w      = (const float*)d_in[15];
    const float* fc1b      = (const float*)d_in[16];
    const float* fc2w      = (const float*)d_in[17];
    const float* fc2b      = (const float*)d_in[18];

    const int N = in_sizes[0] / NODE_DIM;   // 50000
    const int E = in_sizes[1] / 3;          // 1000000
    const int G = out_size;                 // 128
    const int NB = (N + 255) / 256;         // 196 scan blocks

    // Workspace layout (identical footprint class to R8 — proven to fit).
    char* p = (char*)d_ws;
    float* msg    = (float*)p;  p += (size_t)E * 32 * 4;   // [E,32]
    int*   perm   = (int*)p;    p += (size_t)E * 4;        // [E]
    int*   rowptr = (int*)p;    p += (size_t)(N + 1) * 4;  // [N+1]
    int*   nxt    = (int*)p;    p += (size_t)N * 4;        // [N]
    int*   cnt    = (int*)p;    p += (size_t)N * 4;        // [N]   (zeroed)
    float* gsum   = (float*)p;  p += (size_t)G * 32 * 4;   // [G,32] (zeroed)
    int*   bsum   = (int*)p;    p += 256 * 4;              // [<=256]
    int*   boff   = (int*)p;    p += 256 * 4;              // [<=256]

    // cnt and gsum are adjacent -> one memset covers both.
    (void)hipMemsetAsync(cnt, 0, (size_t)N * 4 + (size_t)G * 32 * 4, stream);

    hist_kernel   <<<(E + 255) / 256, 256, 0, stream>>>(eidx, cnt, E);
    scan1_kernel  <<<NB, 256, 0, stream>>>(cnt, rowptr, bsum, N);
    scan2_kernel  <<<1, 256, 0, stream>>>(bsum, boff, NB);
    scan3_kernel  <<<NB, 256, 0, stream>>>(rowptr, nxt, boff, N, E);
    scatter_kernel<<<(E + 255) / 256, 256, 0, stream>>>(eidx, nxt, perm, E);
    edge_kernel_csr<<<2048, 256, 0, stream>>>(x, ea, eidx, perm,
                                              W1, b1, W2, b2, msg, E);
    gather_pool_kernel<<<(N + 7) / 8, 256, 0, stream>>>(msg, rowptr, x, root,
                                                        conv_bias, batch, gsum, N);
    mlp_kernel<<<G, 128, 0, stream>>>(gsum, batch, ratios, ids, emb,
                                      fc0w, fc0b, fc1w, fc1b, fc2w, fc2b,
                                      (float*)d_out, N);
}

// Round 10
// 343.212 us; speedup vs baseline: 1.3221x; 1.0456x over previous
//
#include <hip/hip_runtime.h>

#define NODE_DIM 8

typedef __attribute__((ext_vector_type(8))) short short8;
typedef __attribute__((ext_vector_type(4))) float f32x4;

// 8-term dot; param must not be named w/x/y/z (macro hits member access).
#define DOT8(xv, WT) ((xv)[0]*(WT)[0] + (xv)[1]*(WT)[1] + (xv)[2]*(WT)[2] + (xv)[3]*(WT)[3] + \
                      (xv)[4]*(WT)[4] + (xv)[5]*(WT)[5] + (xv)[6]*(WT)[6] + (xv)[7]*(WT)[7])

// RNE fp32->bf16, packed pair.
static __device__ __forceinline__ unsigned pk_bf16(float a, float b) {
    unsigned ua = __float_as_uint(a), ub = __float_as_uint(b);
    ua = (ua + 0x7fffu + ((ua >> 16) & 1u)) >> 16;
    ub = (ub + 0x7fffu + ((ub >> 16) & 1u)) & 0xffff0000u;
    return (ua & 0xffffu) | ub;
}

// ===========================================================================
// CSR build: histogram -> 3-stage scan -> record scatter (16B sorted records,
// R9: perm-indirection cost 142MB of line-amplified gathers in the edge kernel).
// ===========================================================================
__global__ __launch_bounds__(256)
void hist_kernel(const int* __restrict__ eidx, int* __restrict__ cnt, int E)
{
    const int e = blockIdx.x * blockDim.x + threadIdx.x;
    if (e < E) atomicAdd(&cnt[eidx[E + e]], 1);
}

__global__ __launch_bounds__(256)
void scan1_kernel(const int* __restrict__ cnt, int* __restrict__ rowptr,
                  int* __restrict__ bsum, int N)
{
    __shared__ int sh[256];
    const int t = threadIdx.x;
    const int i = blockIdx.x * 256 + t;
    const int v = (i < N) ? cnt[i] : 0;
    sh[t] = v;
    __syncthreads();
#pragma unroll
    for (int off = 1; off < 256; off <<= 1) {
        int add = 0;
        if (t >= off) add = sh[t - off];
        __syncthreads();
        if (t >= off) sh[t] += add;
        __syncthreads();
    }
    if (i < N) rowptr[i] = sh[t] - v;
    if (t == 255) bsum[blockIdx.x] = sh[255];
}

__global__ __launch_bounds__(256)
void scan2_kernel(const int* __restrict__ bsum, int* __restrict__ boff, int NB)
{
    __shared__ int sh[256];
    const int t = threadIdx.x;
    const int v = (t < NB) ? bsum[t] : 0;
    sh[t] = v;
    __syncthreads();
#pragma unroll
    for (int off = 1; off < 256; off <<= 1) {
        int add = 0;
        if (t >= off) add = sh[t - off];
        __syncthreads();
        if (t >= off) sh[t] += add;
        __syncthreads();
    }
    if (t < NB) boff[t] = sh[t] - v;
}

__global__ __launch_bounds__(256)
void scan3_kernel(int* __restrict__ rowptr, int* __restrict__ nxt,
                  const int* __restrict__ boff, int N, int E)
{
    const int i = blockIdx.x * 256 + threadIdx.x;
    if (i < N) {
        const int r = rowptr[i] + boff[i >> 8];
        rowptr[i] = r;
        nxt[i]    = r;
    }
    if (i == 0) rowptr[N] = E;
}

// Scatter full edge records into dst-sorted order: rec = (src, ea0, ea1, ea2),
// dstA = dst.  Edge kernel then reads exclusively coalesced streams.
__global__ __launch_bounds__(256)
void scatter_kernel(const int* __restrict__ eidx, const float* __restrict__ ea,
                    int* __restrict__ nxt, int4* __restrict__ rec,
                    int* __restrict__ dstA, int E)
{
    const int e = blockIdx.x * blockDim.x + threadIdx.x;
    if (e < E) {
        const int d   = eidx[E + e];
        const int pos = atomicAdd(&nxt[d], 1);
        int4 r;
        r.x = eidx[e];
        r.y = __float_as_int(ea[3 * e]);
        r.z = __float_as_int(ea[3 * e + 1]);
        r.w = __float_as_int(ea[3 * e + 2]);
        rec[pos]  = r;
        dstA[pos] = d;
    }
}

// ===========================================================================
// Fused edge kernel: MFMA message GEMM + in-LDS segment reduction.
//   Block = 4 waves = 64-edge dst-sorted tile.  Per wave: 16 edges,
//   [16,288]@[288,32] via 18x mfma_f32_16x16x32_bf16 (B = W2R + b2 row-ext
//   staged bf16 in LDS, A-frag a_j = h[e,4kk+q]*x[e,j], no shuffle).
//   C tiles -> lds_c[64][33] (stride 33: reduce-phase reads conflict-free),
//   then run-length segment reduce over the sorted dst column issues ~3.6
//   atomics/edge into s[N,32] (6.4MB, L2-resident).  NO msg buffer
//   (R9: msg round-trip was 253MB of HBM traffic).
// ===========================================================================
__global__ __launch_bounds__(256)
void edge_kernel_fused(const float* __restrict__ x,
                       const int4* __restrict__ rec,
                       const int* __restrict__ dstA,
                       const float* __restrict__ W1, const float* __restrict__ b1,
                       const float* __restrict__ W2, const float* __restrict__ b2,
                       float* __restrict__ s, int E)
{
    __shared__ __align__(16) short lds_b[18 * 64 * 8];   // 18 KB B fragments
    __shared__ float lds_c[64 * 33];                     // 8.25 KB C tile
    __shared__ int   lds_d[64];                          // tile dst column

    const int t = threadIdx.x;

    // ---- stage B fragments (bf16, frag-order) once per block ----
    for (int f = t; f < 18 * 64 * 8; f += 256) {
        const int j   = f & 7;
        const int ln  = (f >> 3) & 63;
        const int fid = f >> 9;
        const int kk  = fid >> 1, ot = fid & 1;
        const int qq  = ln >> 4, ol = ln & 15;
        float v;
        if (kk < 8) v = W2[(kk * 4 + qq) * 256 + j * 32 + ot * 16 + ol];
        else        v = (qq == 0) ? b2[j * 32 + ot * 16 + ol] : 0.f;
        unsigned uv = __float_as_uint(v);
        uv = (uv + 0x7fffu + ((uv >> 16) & 1u)) >> 16;
        lds_b[f] = (short)uv;
    }

    const int lane = t & 63;
    const int e_l  = lane & 15;
    const int q    = lane >> 4;
    const int wv   = t >> 6;        // wave in block: 16-edge subtile

    float w10[8], w11[8], w12[8], b1r[8];
#pragma unroll
    for (int t2 = 0; t2 < 8; ++t2) {
        const int k = 4 * t2 + q;
        w10[t2] = W1[k]; w11[t2] = W1[32 + k]; w12[t2] = W1[64 + k]; b1r[t2] = b1[k];
    }
    __syncthreads();   // B staged

    const int ntile = (E + 63) >> 6;

    for (int tile = blockIdx.x; tile < ntile; tile += gridDim.x) {
        const int tbase = tile << 6;

        if (t < 64) lds_d[t] = (tbase + t < E) ? dstA[tbase + t] : -1;

        int slot = tbase + wv * 16 + e_l;
        if (slot >= E) slot = E - 1;
        const int4  rcd = rec[slot];                       // coalesced 16B
        const int   src = rcd.x;
        const float ea0 = __int_as_float(rcd.y);
        const float ea1 = __int_as_float(rcd.z);
        const float ea2 = __int_as_float(rcd.w);
        const float4 xa = *(const float4*)(x + (size_t)(unsigned)src * 8);
        const float4 xb = *(const float4*)(x + (size_t)(unsigned)src * 8 + 4);
        const float xr[8] = {xa.x, xa.y, xa.z, xa.w, xb.x, xb.y, xb.z, xb.w};

        float h[8];
#pragma unroll
        for (int t2 = 0; t2 < 8; ++t2) {
            const float z = b1r[t2] + ea0 * w10[t2] + ea1 * w11[t2] + ea2 * w12[t2];
            h[t2] = z > 0.f ? z : 0.f;
        }

        f32x4 acc0 = {0.f, 0.f, 0.f, 0.f};
        f32x4 acc1 = {0.f, 0.f, 0.f, 0.f};

#pragma unroll
        for (int kk = 0; kk < 9; ++kk) {
            const float hk = (kk < 8) ? h[kk] : 1.f;
            union { short8 v; unsigned u[4]; } af;
#pragma unroll
            for (int p = 0; p < 4; ++p)
                af.u[p] = pk_bf16(hk * xr[2 * p], hk * xr[2 * p + 1]);
            const short8 bf0 = *(const short8*)&lds_b[((kk * 2 + 0) * 64 + lane) * 8];
            const short8 bf1 = *(const short8*)&lds_b[((kk * 2 + 1) * 64 + lane) * 8];
            acc0 = __builtin_amdgcn_mfma_f32_16x16x32_bf16(af.v, bf0, acc0, 0, 0, 0);
            acc1 = __builtin_amdgcn_mfma_f32_16x16x32_bf16(af.v, bf1, acc1, 0, 0, 0);
        }

        // C tile to LDS: row = local edge slot, col = output o.
#pragma unroll
        for (int r = 0; r < 4; ++r) {
            const int row = wv * 16 + q * 4 + r;
            lds_c[row * 33 + e_l]      = acc0[r];
            lds_c[row * 33 + 16 + e_l] = acc1[r];
        }
        __syncthreads();

        // Segment reduce: 128 threads = 32 cols x 4 chunks of 16 rows.
        // dst is sorted within the tile -> run-length accumulate.
        if (t < 128) {
            const int o  = t & 31;
            const int ch = t >> 5;
            const int rlo = ch * 16, rhi = rlo + 16;
            int   cur = -1;
            float run = 0.f;
            for (int r2 = rlo; r2 < rhi; ++r2) {
                const int d = lds_d[r2];
                if (d < 0) break;
                const float v = lds_c[r2 * 33 + o];
                if (d != cur) {
                    if (cur >= 0) atomicAdd(&s[(size_t)cur * 32 + o], run);
                    cur = d; run = v;
                } else {
                    run += v;
                }
            }
            if (cur >= 0) atomicAdd(&s[(size_t)cur * 32 + o], run);
        }
        __syncthreads();
    }
}

// ===========================================================================
// Node transform + pool: v = relu(s/cnt + x@root + cb); block-local pool ->
// gsum atomics.  s is 6.4MB (L2-hot).
// ===========================================================================
__global__ __launch_bounds__(256)
void node_pool_kernel(const float* __restrict__ s,
                      const int* __restrict__ cnt,
                      const float* __restrict__ x,
                      const float* __restrict__ root,
                      const float* __restrict__ conv_bias,
                      const int* __restrict__ batch,
                      float* __restrict__ gsum, int N)
{
    __shared__ float red[256];
    const int t    = threadIdx.x;
    const int o    = t & 31;
    const int slot = t >> 5;
    const int base = blockIdx.x * 8;
    const int n    = base + slot;

    float rootr[8];
#pragma unroll
    for (int i = 0; i < 8; ++i) rootr[i] = root[i * 32 + o];
    const float cb = conv_bias[o];

    float v = 0.f;
    int   b = 0;
    if (n < N) {
        b = batch[n];
        const int   c    = cnt[n];
        const float rinv = 1.f / (float)(c > 1 ? c : 1);
        const float* xp  = x + (size_t)n * 8;
        float xv[8];
#pragma unroll
        for (int i = 0; i < 8; ++i) xv[i] = xp[i];
        const float t2 = s[(size_t)n * 32 + o] * rinv + cb + DOT8(xv, rootr);
        v = t2 > 0.f ? t2 : 0.f;
    }

    const int nlast  = (base + 7 < N) ? base + 7 : N - 1;
    const int bfirst = batch[base];
    const int blast  = batch[nlast];

    if (bfirst == blast && base + 7 < N) {
        red[t] = v;
        __syncthreads();
        if (t < 32) {
            float p = 0.f;
#pragma unroll
            for (int c2 = 0; c2 < 8; ++c2) p += red[t + 32 * c2];
            atomicAdd(&gsum[bfirst * 32 + t], p);
        }
    } else {
        if (n < N) atomicAdd(&gsum[b * 32 + o], v);
    }
}

// ===========================================================================
// MLP head: one 128-thread block per graph.
// ===========================================================================
__global__ __launch_bounds__(128)
void mlp_kernel(const float* __restrict__ gsum,
                const int* __restrict__ batch,
                const float* __restrict__ ratios,
                const int* __restrict__ ids,
                const float* __restrict__ emb,
                const float* __restrict__ fc0w, const float* __restrict__ fc0b,
                const float* __restrict__ fc1w, const float* __restrict__ fc1b,
                const float* __restrict__ fc2w, const float* __restrict__ fc2b,
                float* __restrict__ out, int N)
{
    __shared__ float zs[96];
    __shared__ float z1[64];
    __shared__ float z2[32];
    __shared__ int seg[2];

    const int g = blockIdx.x;
    const int t = threadIdx.x;

    if (t < 2) {
        const int target = g + t;
        int lo = 0, hi = N;
        while (lo < hi) {
            const int mid = (lo + hi) >> 1;
            if (batch[mid] < target) lo = mid + 1; else hi = mid;
        }
        seg[t] = lo;
    }
    __syncthreads();

    float c = (float)(seg[1] - seg[0]);
    if (c < 1.f) c = 1.f;

    if (t < 32) zs[t] = gsum[g * 32 + t] / c;
    if (t >= 32 && t < 96) {
        const int j = t - 32;
        float u = 0.f;
#pragma unroll
        for (int r = 0; r < 5; ++r) u += ratios[r] * emb[(size_t)ids[r] * 64 + j];
        zs[32 + j] = u;
    }
    __syncthreads();

    if (t < 64) {
        float a = fc0b[t];
        for (int k = 0; k < 96; ++k) a += zs[k] * fc0w[k * 64 + t];
        z1[t] = a > 0.f ? a : 0.f;
    }
    __syncthreads();

    if (t < 32) {
        float a = fc1b[t];
        for (int k = 0; k < 64; ++k) a += z1[k] * fc1w[k * 32 + t];
        z2[t] = a > 0.f ? a : 0.f;
    }
    __syncthreads();

    if (t == 0) {
        float a = fc2b[0];
        for (int k = 0; k < 32; ++k) a += z2[k] * fc2w[k];
        out[g] = a;
    }
}

// ---------------------------------------------------------------------------
extern "C" void kernel_launch(void* const* d_in, const int* in_sizes, int n_in,
                              void* d_out, int out_size, void* d_ws, size_t ws_size,
                              hipStream_t stream)
{
    const float* x         = (const float*)d_in[0];
    const float* ea        = (const float*)d_in[1];
    const float* ratios    = (const float*)d_in[2];
    const int*   eidx      = (const int*)  d_in[3];
    const int*   batch     = (const int*)  d_in[4];
    const int*   ids       = (const int*)  d_in[5];
    const float* W1        = (const float*)d_in[6];
    const float* b1        = (const float*)d_in[7];
    const float* W2        = (const float*)d_in[8];
    const float* b2        = (const float*)d_in[9];
    const float* emb       = (const float*)d_in[10];
    const float* root      = (const float*)d_in[11];
    const float* conv_bias = (const float*)d_in[12];
    const float* fc0w      = (const float*)d_in[13];
    const float* fc0b      = (const float*)d_in[14];
    const float* fc1w      = (const float*)d_in[15];
    const float* fc1b      = (const float*)d_in[16];
    const float* fc2w      = (const float*)d_in[17];
    const float* fc2b      = (const float*)d_in[18];

    const int N = in_sizes[0] / NODE_DIM;   // 50000
    const int E = in_sizes[1] / 3;          // 1000000
    const int G = out_size;                 // 128
    const int NB = (N + 255) / 256;         // scan blocks

    // Workspace (~27MB; prior 133MB layout fit, so no fallback needed).
    char* p = (char*)d_ws;
    int4*  rec    = (int4*)p;   p += (size_t)E * 16;      // [E] 16B records
    int*   dstA   = (int*)p;    p += (size_t)E * 4;       // [E]
    int*   rowptr = (int*)p;    p += (size_t)(N + 1) * 4; // [N+1]
    int*   nxt    = (int*)p;    p += (size_t)N * 4;       // [N]
    float* s      = (float*)p;  p += (size_t)N * 32 * 4;  // [N,32]  (zeroed)
    int*   cnt    = (int*)p;    p += (size_t)N * 4;       // [N]     (zeroed)
    float* gsum   = (float*)p;  p += (size_t)G * 32 * 4;  // [G,32]  (zeroed)
    int*   bsum   = (int*)p;    p += 256 * 4;
    int*   boff   = (int*)p;    p += 256 * 4;

    // s, cnt, gsum adjacent -> one memset.
    (void)hipMemsetAsync(s, 0, (size_t)N * 32 * 4 + (size_t)N * 4 + (size_t)G * 32 * 4, stream);

    hist_kernel   <<<(E + 255) / 256, 256, 0, stream>>>(eidx, cnt, E);
    scan1_kernel  <<<NB, 256, 0, stream>>>(cnt, rowptr, bsum, N);
    scan2_kernel  <<<1, 256, 0, stream>>>(bsum, boff, NB);
    scan3_kernel  <<<NB, 256, 0, stream>>>(rowptr, nxt, boff, N, E);
    scatter_kernel<<<(E + 255) / 256, 256, 0, stream>>>(eidx, ea, nxt, rec, dstA, E);
    edge_kernel_fused<<<2048, 256, 0, stream>>>(x, rec, dstA, W1, b1, W2, b2, s, E);
    node_pool_kernel<<<(N + 7) / 8, 256, 0, stream>>>(s, cnt, x, root, conv_bias,
                                                      batch, gsum, N);
    mlp_kernel<<<G, 128, 0, stream>>>(gsum, batch, ratios, ids, emb,
                                      fc0w, fc0b, fc1w, fc1b, fc2w, fc2b,
                                      (float*)d_out, N);
}

// Round 11
// 332.155 us; speedup vs baseline: 1.3662x; 1.0333x over previous
//
#include <hip/hip_runtime.h>

#define NODE_DIM 8

typedef __attribute__((ext_vector_type(8))) short short8;
typedef __attribute__((ext_vector_type(4))) float f32x4;

// 8-term dot; param must not be named w/x/y/z (macro hits member access).
#define DOT8(xv, WT) ((xv)[0]*(WT)[0] + (xv)[1]*(WT)[1] + (xv)[2]*(WT)[2] + (xv)[3]*(WT)[3] + \
                      (xv)[4]*(WT)[4] + (xv)[5]*(WT)[5] + (xv)[6]*(WT)[6] + (xv)[7]*(WT)[7])

// fp32 pair -> packed bf16 via round-half-up + byte-perm (3 VALU vs 7 for RNE;
// differs from RNE only on exact-tie mantissas -> numerically equivalent here).
static __device__ __forceinline__ unsigned pk2_bf16(float a, float b) {
    const unsigned ua = __float_as_uint(a) + 0x8000u;
    const unsigned ub = __float_as_uint(b) + 0x8000u;
    // D.b0=ua.b2, D.b1=ua.b3, D.b2=ub.b2, D.b3=ub.b3
    return __builtin_amdgcn_perm(ub, ua, 0x07060302u);
}

// RNE scalar (used only for B staging, once per block).
static __device__ __forceinline__ short bf16_rne(float v) {
    unsigned u = __float_as_uint(v);
    u = (u + 0x7fffu + ((u >> 16) & 1u)) >> 16;
    return (short)u;
}

// ===========================================================================
// CSR build: histogram -> 3-stage scan (+dstA expansion) -> record scatter.
// ===========================================================================
__global__ __launch_bounds__(256)
void hist_kernel(const int* __restrict__ eidx, int* __restrict__ cnt, int E)
{
    const int e = blockIdx.x * blockDim.x + threadIdx.x;
    if (e < E) atomicAdd(&cnt[eidx[E + e]], 1);
}

__global__ __launch_bounds__(256)
void scan1_kernel(const int* __restrict__ cnt, int* __restrict__ rowptr,
                  int* __restrict__ bsum, int N)
{
    __shared__ int sh[256];
    const int t = threadIdx.x;
    const int i = blockIdx.x * 256 + t;
    const int v = (i < N) ? cnt[i] : 0;
    sh[t] = v;
    __syncthreads();
#pragma unroll
    for (int off = 1; off < 256; off <<= 1) {
        int add = 0;
        if (t >= off) add = sh[t - off];
        __syncthreads();
        if (t >= off) sh[t] += add;
        __syncthreads();
    }
    if (i < N) rowptr[i] = sh[t] - v;
    if (t == 255) bsum[blockIdx.x] = sh[255];
}

__global__ __launch_bounds__(256)
void scan2_kernel(const int* __restrict__ bsum, int* __restrict__ boff, int NB)
{
    __shared__ int sh[256];
    const int t = threadIdx.x;
    const int v = (t < NB) ? bsum[t] : 0;
    sh[t] = v;
    __syncthreads();
#pragma unroll
    for (int off = 1; off < 256; off <<= 1) {
        int add = 0;
        if (t >= off) add = sh[t - off];
        __syncthreads();
        if (t >= off) sh[t] += add;
        __syncthreads();
    }
    if (t < NB) boff[t] = sh[t] - v;
}

// Stage 3: finalize rowptr/nxt AND expand dstA[r]=n for r in [row, row+cnt[n])
// (sequential writes; removes the 4B random dst write from the scatter).
__global__ __launch_bounds__(256)
void scan3_kernel(int* __restrict__ rowptr, int* __restrict__ nxt,
                  const int* __restrict__ boff, const int* __restrict__ cnt,
                  int* __restrict__ dstA, int N, int E)
{
    const int i = blockIdx.x * 256 + threadIdx.x;
    if (i < N) {
        const int r = rowptr[i] + boff[i >> 8];
        rowptr[i] = r;
        nxt[i]    = r;
        const int c = cnt[i];
        for (int p2 = 0; p2 < c; ++p2) dstA[r + p2] = i;
    }
    if (i == 0) rowptr[N] = E;
}

// Scatter edge records into dst-sorted order: rec = (src, ea0, ea1, ea2).
__global__ __launch_bounds__(256)
void scatter_kernel(const int* __restrict__ eidx, const float* __restrict__ ea,
                    int* __restrict__ nxt, int4* __restrict__ rec, int E)
{
    const int e = blockIdx.x * blockDim.x + threadIdx.x;
    if (e < E) {
        const int d   = eidx[E + e];
        const int pos = atomicAdd(&nxt[d], 1);
        int4 r;
        r.x = eidx[e];
        r.y = __float_as_int(ea[3 * e]);
        r.z = __float_as_int(ea[3 * e + 1]);
        r.w = __float_as_int(ea[3 * e + 2]);
        rec[pos] = r;
    }
}

// ===========================================================================
// Fused edge kernel: MFMA message GEMM + in-LDS segment reduction.
//   Block = 4 waves = 64-edge dst-sorted tile; per wave [16,288]@[288,32]
//   (18x mfma_f32_16x16x32_bf16; B = W2R+b2 staged bf16 in LDS, A-frag
//   a_j = h[e,4kk+q]*x[e,j], packed via pk2_bf16 = 3 VALU/pair).
//   Software-pipelined: next tile's rec prefetched during MFMA, x after.
//   Reduce: 256 threads = 32 cols x 8 chunks of 8 rows, run-length atomics
//   into s[N,32] (L2-resident).
// ===========================================================================
__global__ __launch_bounds__(256)
void edge_kernel_fused(const float* __restrict__ x,
                       const int4* __restrict__ rec,
                       const int* __restrict__ dstA,
                       const float* __restrict__ W1, const float* __restrict__ b1,
                       const float* __restrict__ W2, const float* __restrict__ b2,
                       float* __restrict__ s, int E)
{
    __shared__ __align__(16) short lds_b[18 * 64 * 8];   // 18 KB B fragments
    __shared__ float lds_c[64 * 33];                     // 8.25 KB C tile
    __shared__ int   lds_d[64];                          // tile dst column

    const int t = threadIdx.x;

    // ---- stage B fragments (bf16 RNE, frag-order) once per block ----
    for (int f = t; f < 18 * 64 * 8; f += 256) {
        const int j   = f & 7;
        const int ln  = (f >> 3) & 63;
        const int fid = f >> 9;
        const int kk  = fid >> 1, ot = fid & 1;
        const int qq  = ln >> 4, ol = ln & 15;
        float v;
        if (kk < 8) v = W2[(kk * 4 + qq) * 256 + j * 32 + ot * 16 + ol];
        else        v = (qq == 0) ? b2[j * 32 + ot * 16 + ol] : 0.f;
        lds_b[f] = bf16_rne(v);
    }

    const int lane = t & 63;
    const int e_l  = lane & 15;
    const int q    = lane >> 4;
    const int wv   = t >> 6;

    float w10[8], w11[8], w12[8], b1r[8];
#pragma unroll
    for (int t2 = 0; t2 < 8; ++t2) {
        const int k = 4 * t2 + q;
        w10[t2] = W1[k]; w11[t2] = W1[32 + k]; w12[t2] = W1[64 + k]; b1r[t2] = b1[k];
    }
    __syncthreads();   // B staged

    const int ntile = (E + 63) >> 6;
    int tile = blockIdx.x;
    if (tile >= ntile) return;

    // ---- prologue: load first tile's record + x ----
    int slot0 = (tile << 6) + wv * 16 + e_l; if (slot0 >= E) slot0 = E - 1;
    int4   rcd = rec[slot0];
    float4 xa  = *(const float4*)(x + (size_t)(unsigned)rcd.x * 8);
    float4 xb  = *(const float4*)(x + (size_t)(unsigned)rcd.x * 8 + 4);

    for (; tile < ntile; tile += gridDim.x) {
        const int tbase = tile << 6;

        // dst column for this tile (coalesced; consumed by reduce phase)
        int dval = 0;
        if (t < 64) dval = (tbase + t < E) ? dstA[tbase + t] : -1;

        // h from current record
        const float ea0 = __int_as_float(rcd.y);
        const float ea1 = __int_as_float(rcd.z);
        const float ea2 = __int_as_float(rcd.w);
        float h[8];
#pragma unroll
        for (int t2 = 0; t2 < 8; ++t2) {
            const float z = b1r[t2] + ea0 * w10[t2] + ea1 * w11[t2] + ea2 * w12[t2];
            h[t2] = z > 0.f ? z : 0.f;
        }
        const float xr[8] = {xa.x, xa.y, xa.z, xa.w, xb.x, xb.y, xb.z, xb.w};

        // prefetch next tile's record (latency hidden under MFMA phase)
        const int tn = tile + gridDim.x;
        int4 rcd_n = rcd;
        if (tn < ntile) {
            int sl = (tn << 6) + wv * 16 + e_l; if (sl >= E) sl = E - 1;
            rcd_n = rec[sl];
        }

        // ---- MFMA phase ----
        f32x4 acc0 = {0.f, 0.f, 0.f, 0.f};
        f32x4 acc1 = {0.f, 0.f, 0.f, 0.f};
#pragma unroll
        for (int kk = 0; kk < 9; ++kk) {
            const float hk = (kk < 8) ? h[kk] : 1.f;
            union { short8 v; unsigned u[4]; } af;
#pragma unroll
            for (int p2 = 0; p2 < 4; ++p2)
                af.u[p2] = pk2_bf16(hk * xr[2 * p2], hk * xr[2 * p2 + 1]);
            const short8 bf0 = *(const short8*)&lds_b[((kk * 2 + 0) * 64 + lane) * 8];
            const short8 bf1 = *(const short8*)&lds_b[((kk * 2 + 1) * 64 + lane) * 8];
            acc0 = __builtin_amdgcn_mfma_f32_16x16x32_bf16(af.v, bf0, acc0, 0, 0, 0);
            acc1 = __builtin_amdgcn_mfma_f32_16x16x32_bf16(af.v, bf1, acc1, 0, 0, 0);
        }

        // prefetch next tile's x (rcd_n should have landed during MFMA)
        float4 xa_n = xa, xb_n = xb;
        if (tn < ntile) {
            xa_n = *(const float4*)(x + (size_t)(unsigned)rcd_n.x * 8);
            xb_n = *(const float4*)(x + (size_t)(unsigned)rcd_n.x * 8 + 4);
        }

        __syncthreads();   // previous reduce finished with lds_c/lds_d

        // C tile + dst column to LDS
#pragma unroll
        for (int r = 0; r < 4; ++r) {
            const int row = wv * 16 + q * 4 + r;
            lds_c[row * 33 + e_l]      = acc0[r];
            lds_c[row * 33 + 16 + e_l] = acc1[r];
        }
        if (t < 64) lds_d[t] = dval;
        __syncthreads();

        // ---- segment reduce: 32 cols x 8 chunks of 8 rows ----
        {
            const int o   = t & 31;
            const int rlo = (t >> 5) * 8;
            int   cur = -1;
            float run = 0.f;
#pragma unroll
            for (int r2 = rlo; r2 < rlo + 8; ++r2) {
                const int d = lds_d[r2];
                const float v = lds_c[r2 * 33 + o];
                if (d != cur) {
                    if (cur >= 0) atomicAdd(&s[(size_t)cur * 32 + o], run);
                    cur = d; run = v;
                } else {
                    run += v;
                }
            }
            if (cur >= 0) atomicAdd(&s[(size_t)cur * 32 + o], run);
        }

        // rotate pipeline regs
        rcd = rcd_n; xa = xa_n; xb = xb_n;
    }
}

// ===========================================================================
// Node transform + pool: v = relu(s/cnt + x@root + cb); block-local pool ->
// gsum atomics.
// ===========================================================================
__global__ __launch_bounds__(256)
void node_pool_kernel(const float* __restrict__ s,
                      const int* __restrict__ cnt,
                      const float* __restrict__ x,
                      const float* __restrict__ root,
                      const float* __restrict__ conv_bias,
                      const int* __restrict__ batch,
                      float* __restrict__ gsum, int N)
{
    __shared__ float red[256];
    const int t    = threadIdx.x;
    const int o    = t & 31;
    const int slot = t >> 5;
    const int base = blockIdx.x * 8;
    const int n    = base + slot;

    float rootr[8];
#pragma unroll
    for (int i = 0; i < 8; ++i) rootr[i] = root[i * 32 + o];
    const float cb = conv_bias[o];

    float v = 0.f;
    int   b = 0;
    if (n < N) {
        b = batch[n];
        const int   c    = cnt[n];
        const float rinv = 1.f / (float)(c > 1 ? c : 1);
        const float* xp  = x + (size_t)n * 8;
        float xv[8];
#pragma unroll
        for (int i = 0; i < 8; ++i) xv[i] = xp[i];
        const float t2 = s[(size_t)n * 32 + o] * rinv + cb + DOT8(xv, rootr);
        v = t2 > 0.f ? t2 : 0.f;
    }

    const int nlast  = (base + 7 < N) ? base + 7 : N - 1;
    const int bfirst = batch[base];
    const int blast  = batch[nlast];

    if (bfirst == blast && base + 7 < N) {
        red[t] = v;
        __syncthreads();
        if (t < 32) {
            float p2 = 0.f;
#pragma unroll
            for (int c2 = 0; c2 < 8; ++c2) p2 += red[t + 32 * c2];
            atomicAdd(&gsum[bfirst * 32 + t], p2);
        }
    } else {
        if (n < N) atomicAdd(&gsum[b * 32 + o], v);
    }
}

// ===========================================================================
// MLP head: one 128-thread block per graph.
// ===========================================================================
__global__ __launch_bounds__(128)
void mlp_kernel(const float* __restrict__ gsum,
                const int* __restrict__ batch,
                const float* __restrict__ ratios,
                const int* __restrict__ ids,
                const float* __restrict__ emb,
                const float* __restrict__ fc0w, const float* __restrict__ fc0b,
                const float* __restrict__ fc1w, const float* __restrict__ fc1b,
                const float* __restrict__ fc2w, const float* __restrict__ fc2b,
                float* __restrict__ out, int N)
{
    __shared__ float zs[96];
    __shared__ float z1[64];
    __shared__ float z2[32];
    __shared__ int seg[2];

    const int g = blockIdx.x;
    const int t = threadIdx.x;

    if (t < 2) {
        const int target = g + t;
        int lo = 0, hi = N;
        while (lo < hi) {
            const int mid = (lo + hi) >> 1;
            if (batch[mid] < target) lo = mid + 1; else hi = mid;
        }
        seg[t] = lo;
    }
    __syncthreads();

    float c = (float)(seg[1] - seg[0]);
    if (c < 1.f) c = 1.f;

    if (t < 32) zs[t] = gsum[g * 32 + t] / c;
    if (t >= 32 && t < 96) {
        const int j = t - 32;
        float u = 0.f;
#pragma unroll
        for (int r = 0; r < 5; ++r) u += ratios[r] * emb[(size_t)ids[r] * 64 + j];
        zs[32 + j] = u;
    }
    __syncthreads();

    if (t < 64) {
        float a = fc0b[t];
        for (int k = 0; k < 96; ++k) a += zs[k] * fc0w[k * 64 + t];
        z1[t] = a > 0.f ? a : 0.f;
    }
    __syncthreads();

    if (t < 32) {
        float a = fc1b[t];
        for (int k = 0; k < 64; ++k) a += z1[k] * fc1w[k * 32 + t];
        z2[t] = a > 0.f ? a : 0.f;
    }
    __syncthreads();

    if (t == 0) {
        float a = fc2b[0];
        for (int k = 0; k < 32; ++k) a += z2[k] * fc2w[k];
        out[g] = a;
    }
}

// ---------------------------------------------------------------------------
extern "C" void kernel_launch(void* const* d_in, const int* in_sizes, int n_in,
                              void* d_out, int out_size, void* d_ws, size_t ws_size,
                              hipStream_t stream)
{
    const float* x         = (const float*)d_in[0];
    const float* ea        = (const float*)d_in[1];
    const float* ratios    = (const float*)d_in[2];
    const int*   eidx      = (const int*)  d_in[3];
    const int*   batch     = (const int*)  d_in[4];
    const int*   ids       = (const int*)  d_in[5];
    const float* W1        = (const float*)d_in[6];
    const float* b1        = (const float*)d_in[7];
    const float* W2        = (const float*)d_in[8];
    const float* b2        = (const float*)d_in[9];
    const float* emb       = (const float*)d_in[10];
    const float* root      = (const float*)d_in[11];
    const float* conv_bias = (const float*)d_in[12];
    const float* fc0w      = (const float*)d_in[13];
    const float* fc0b      = (const float*)d_in[14];
    const float* fc1w      = (const float*)d_in[15];
    const float* fc1b      = (const float*)d_in[16];
    const float* fc2w      = (const float*)d_in[17];
    const float* fc2b      = (const float*)d_in[18];

    const int N = in_sizes[0] / NODE_DIM;   // 50000
    const int E = in_sizes[1] / 3;          // 1000000
    const int G = out_size;                 // 128
    const int NB = (N + 255) / 256;

    char* p = (char*)d_ws;
    int4*  rec    = (int4*)p;   p += (size_t)E * 16;      // [E] 16B sorted records
    int*   dstA   = (int*)p;    p += (size_t)E * 4;       // [E] (expanded, sequential)
    int*   rowptr = (int*)p;    p += (size_t)(N + 1) * 4;
    int*   nxt    = (int*)p;    p += (size_t)N * 4;
    float* s      = (float*)p;  p += (size_t)N * 32 * 4;  // (zeroed)
    int*   cnt    = (int*)p;    p += (size_t)N * 4;       // (zeroed)
    float* gsum   = (float*)p;  p += (size_t)G * 32 * 4;  // (zeroed)
    int*   bsum   = (int*)p;    p += 256 * 4;
    int*   boff   = (int*)p;    p += 256 * 4;

    (void)hipMemsetAsync(s, 0, (size_t)N * 32 * 4 + (size_t)N * 4 + (size_t)G * 32 * 4, stream);

    hist_kernel   <<<(E + 255) / 256, 256, 0, stream>>>(eidx, cnt, E);
    scan1_kernel  <<<NB, 256, 0, stream>>>(cnt, rowptr, bsum, N);
    scan2_kernel  <<<1, 256, 0, stream>>>(bsum, boff, NB);
    scan3_kernel  <<<NB, 256, 0, stream>>>(rowptr, nxt, boff, cnt, dstA, N, E);
    scatter_kernel<<<(E + 255) / 256, 256, 0, stream>>>(eidx, ea, nxt, rec, E);

    const int ntile = (E + 63) >> 6;
    const int grid  = ntile < 4096 ? ntile : 4096;
    edge_kernel_fused<<<grid, 256, 0, stream>>>(x, rec, dstA, W1, b1, W2, b2, s, E);

    node_pool_kernel<<<(N + 7) / 8, 256, 0, stream>>>(s, cnt, x, root, conv_bias,
                                                      batch, gsum, N);
    mlp_kernel<<<G, 128, 0, stream>>>(gsum, batch, ratios, ids, emb,
                                      fc0w, fc0b, fc1w, fc1b, fc2w, fc2b,
                                      (float*)d_out, N);
}